// Round 5
// baseline (464.311 us; speedup 1.0000x reference)
//
#include <hip/hip_runtime.h>

// ConvLSTM2D via MFMA implicit-GEMM. B=8,T=16,H=W=64,Cin=32,F=64,3x3 SAME.
// Round 12: OCCUPANCY attack. R7/R9/R10/R11 (4 different K-loop schedules)
// all measured ~2300 cyc/iter with NOTHING saturated (LDS ~28 of 112 B/cyc,
// MFMA ~27%): the loop is latency-bound and at 2 waves/SIMD the sibling
// waves convoy in-phase, so no TLP fills the dependency gaps. Fix = 4
// waves/SIMD: 256-thr blocks (4 waves), 64-px tile, wave tile 64px x 32ch
// (acc 32 VGPR), P=2 wave-private ring (16 KB), VGPR capped at 128 via
// waves_per_eu(4). Grid gains a x2 n-partition: block nh covers the 4
// gates x 32 f-channels n = {64g + 32nh + [0,32)}; wave w computes gate w
// (nt = 4w + 2nh + {0,1}). Since the LSTM epilogue needs all 4 gates per
// (px,f-ch) and they now live in different waves, a one-time 32 KB LDS
// exchange (aliasing the dead ring+stage regions) reassembles them.
// K-loop stays barrier-free (R7 vmcnt gating): at 4 waves/SIMD the
// hardware scheduler finally has out-of-phase siblings to overlap LDS
// latency with MFMA. Per-CU-iter: MFMA unchanged 621 cyc, LDS reads 96 KB
// (+50% vs R11) -- acceptable: the regime is latency-bound, not LDS-bound.

#define TSTEPS 16

typedef short bf16x8 __attribute__((ext_vector_type(8)));
typedef float f32x4 __attribute__((ext_vector_type(4)));
typedef unsigned int __attribute__((address_space(1))) gu32;
typedef unsigned int __attribute__((address_space(3))) lu32;

__device__ __forceinline__ float hsig(float x) {
    return fminf(fmaxf((x + 3.0f) * (1.0f / 6.0f), 0.0f), 1.0f);
}

__device__ __forceinline__ unsigned short f2bf(float f) {
    union { float f; unsigned int u; } v; v.f = f;
    unsigned int r = v.u + 0x7fffu + ((v.u >> 16) & 1u);  // RNE
    return (unsigned short)(r >> 16);
}

// ---- weight prepack: Wg(3,3,32,256), Ug(3,3,64,256) fp32 -> bf16 B-frags ----
// layout out[s][nt(16)][lane(64)][8]: per (s,nt) one contiguous 1 KB line.
__global__ __launch_bounds__(256)
void prepack_w(const float* __restrict__ Wg, const float* __restrict__ Ug,
               unsigned short* __restrict__ out)
{
    int idx = blockIdx.x * 256 + threadIdx.x;   // 27*16*64 = 27648
    if (idx >= 27648) return;
    int lane = idx & 63;
    int nt   = (idx >> 6) & 15;
    int s    = idx >> 10;
    int col = lane & 15, quad = lane >> 4;
    int n = nt * 16 + col;
    int k0 = quad * 8;
    const float* src;
    if (s < 9) {
        src = Wg + ((size_t)s * 32 + k0) * 256 + n;
    } else {
        int ss = s - 9; int tap = ss >> 1; int half = ss & 1;
        src = Ug + ((size_t)tap * 64 + half * 32 + k0) * 256 + n;
    }
    unsigned short tmp[8];
    #pragma unroll
    for (int j = 0; j < 8; ++j) tmp[j] = f2bf(src[(size_t)j * 256]);
    *(uint4*)(out + (size_t)idx * 8) = *(uint4*)tmp;
}

// ---- one ConvLSTM step (NS = 9 for t==0, 27 otherwise) ----
// block: 256 thr (4 waves), 8x8 px tile, n-half nh (4 gates x 32 f-ch).
template<int NS>
__global__ __launch_bounds__(256)
__attribute__((amdgpu_waves_per_eu(4)))
void convlstm_step(const float* __restrict__ x,       // (B,T,64,64,32) fp32
                   const unsigned short* __restrict__ wpk,
                   const float* __restrict__ bias,    // (256)
                   const unsigned short* __restrict__ h_in, // bf16 (B,64,64,64)
                   float* __restrict__ c_st,          // fp32 (B,64,64,64) = d_out
                   unsigned short* __restrict__ h_out,// bf16 ping
                   int t, int is_last)
{
    constexpr bool HP = (NS == 27);

    // one flat LDS block; epilogue zbuf aliases it (ring dead by then).
    //   [0,8000)      xs_s : 100 px x 40 shorts (x halo, pad 40)
    //   [8000,22400)  hs_s : 100 px x 72 shorts (h halo, pad 72)
    //   [22400,38784) bring: 2 slots x 8 nt x 1 KB
    //   epilogue: zbuf f32[64px][32fch][4gate] = 32768 B over [0,32768)
    __shared__ __align__(16) unsigned char smem[38784];
    unsigned short* xs_s  = (unsigned short*)smem;
    unsigned short* hs_s  = (unsigned short*)(smem + 8000);
    unsigned short* bring = (unsigned short*)(smem + 22400);
    float*          zbuf  = (float*)smem;

    const int tid = threadIdx.x;
    const int gx0 = blockIdx.x * 8;
    const int gy0 = blockIdx.y * 8;
    const int b   = blockIdx.z >> 1;
    const int nh  = blockIdx.z & 1;    // n-half: f-ch [nh*32, nh*32+32)

    const int lane = tid & 63;
    const int w    = tid >> 6;         // wave 0..3 == gate 0..3
    const int quad = lane >> 4;
    const int m    = lane & 15;

    // ---- B DMA: wave w stages its gate's 2 nt for k-step s into slot s&1.
    // global nt = 4w + 2nh + g ; local ring index = 2w + g.
    auto issueDMA = [&](int s) {
        int slot = s & 1;
        #pragma unroll
        for (int g = 0; g < 2; ++g) {
            int ntg = w * 4 + nh * 2 + g;
            const unsigned short* gp = wpk + ((size_t)(s * 16 + ntg) * 64 + lane) * 8;
            unsigned short* lp = bring + ((size_t)(slot * 8 + w * 2 + g)) * 512;  // uniform
            __builtin_amdgcn_global_load_lds((const gu32*)gp, (lu32*)lp, 16, 0, 0);
        }
    };

    // prologue DMAs; the staging __syncthreads (vmcnt(0) drain) certifies them
    issueDMA(0);
    issueDMA(1);

    // ---- stage x halo (fp32 -> bf16), 100 px ----
    {
        const float* xt = x + (((size_t)b * TSTEPS + t) * (size_t)(64 * 64 * 32));
        #pragma unroll 4
        for (int idx = tid; idx < 100 * 8; idx += 256) {
            int pix = idx >> 3, q = idx & 7;
            int iy = pix / 10, ix = pix - iy * 10;
            int gy = gy0 + iy - 1, gx = gx0 + ix - 1;
            unsigned short o[4] = {0, 0, 0, 0};
            if ((unsigned)gy < 64u && (unsigned)gx < 64u) {
                float4 v = *(const float4*)(xt + ((size_t)(gy * 64 + gx) * 32) + q * 4);
                o[0] = f2bf(v.x); o[1] = f2bf(v.y); o[2] = f2bf(v.z); o[3] = f2bf(v.w);
            }
            *(ushort4*)(xs_s + pix * 40 + q * 4) = *(ushort4*)o;
        }
    }
    // ---- stage h halo (bf16 copy, all 64 ch: k-dim, independent of nh) ----
    if constexpr (HP) {
        const unsigned short* hb = h_in + ((size_t)b * (64 * 64 * 64));
        #pragma unroll 4
        for (int idx = tid; idx < 100 * 8; idx += 256) {
            int pix = idx >> 3, q = idx & 7;
            int iy = pix / 10, ix = pix - iy * 10;
            int gy = gy0 + iy - 1, gx = gx0 + ix - 1;
            uint4 v = make_uint4(0u, 0u, 0u, 0u);
            if ((unsigned)gy < 64u && (unsigned)gx < 64u)
                v = *(const uint4*)(hb + ((size_t)(gy * 64 + gx) * 64) + q * 8);
            *(uint4*)(hs_s + pix * 72 + q * 8) = v;
        }
    }
    __syncthreads();   // staging + ring slots 0,1 visible (full vmcnt drain)

    int xb[4], hb_[4];
    #pragma unroll
    for (int mt = 0; mt < 4; ++mt) {
        int p = mt * 16 + m;
        int py = p >> 3, px = p & 7;
        xb[mt]  = (py * 10 + px) * 40 + quad * 8;
        hb_[mt] = (py * 10 + px) * 72 + quad * 8;
    }

    // acc init = bias; n = 64w + 32nh + 16g + col
    f32x4 acc[4][2];   // [mt][g]
    #pragma unroll
    for (int g = 0; g < 2; ++g) {
        float bv = bias[w * 64 + nh * 32 + g * 16 + m];
        f32x4 bi = (f32x4){bv, bv, bv, bv};
        #pragma unroll
        for (int mt = 0; mt < 4; ++mt) acc[mt][g] = bi;
    }

    // ---- K-loop: barrier-free, wave-private vmcnt gating, P=2 ring ----
    #pragma unroll
    for (int s = 0; s < NS; ++s) {
        // certify MY slot-s loads (keep s+1's 2 loads pending)
        if (s + 1 < NS) __builtin_amdgcn_s_waitcnt(0xF72);  // vmcnt(2)
        else            __builtin_amdgcn_s_waitcnt(0xF70);  // vmcnt(0)

        const int slot = s & 1;
        bf16x8 bfr[2];
        #pragma unroll
        for (int g = 0; g < 2; ++g)
            bfr[g] = *(const bf16x8*)(bring + ((size_t)(slot * 8 + w * 2 + g)) * 512 + lane * 8);

        bf16x8 a[4];
        if (s < 9) {
            int taplin = (s / 3) * 10 + (s % 3);
            #pragma unroll
            for (int mt = 0; mt < 4; ++mt)
                a[mt] = *(const bf16x8*)(xs_s + xb[mt] + taplin * 40);
        } else {
            int ss = s - 9, tap = ss >> 1, half = ss & 1;
            int taplin = (tap / 3) * 10 + (tap % 3);
            #pragma unroll
            for (int mt = 0; mt < 4; ++mt)
                a[mt] = *(const bf16x8*)(hs_s + hb_[mt] + taplin * 72 + half * 32);
        }

        #pragma unroll
        for (int g = 0; g < 2; ++g)
            #pragma unroll
            for (int mt = 0; mt < 4; ++mt)
                acc[mt][g] = __builtin_amdgcn_mfma_f32_16x16x32_bf16(a[mt], bfr[g], acc[mt][g], 0, 0, 0);

        // refill slot s&1 for step s+2. sched_barrier keeps the DMA issue
        // after the ds_reads/MFMAs above (no data dep would otherwise
        // order it); the lgkm waits before the MFMAs guarantee the reads
        // of this slot completed.
        if (s + 2 < NS) {
            __builtin_amdgcn_sched_barrier(0);
            issueDMA(s + 2);
        }
    }

    // ---- epilogue: cross-wave gate exchange via LDS, then state update ----
    __syncthreads();   // all waves done with ring/stage regions (zbuf aliases)

    // write z: zbuf[px][fch_local][gate]; px = mt*16 + quad*4 + r,
    // fch_local = 16g + m, gate = w
    #pragma unroll
    for (int mt = 0; mt < 4; ++mt)
        #pragma unroll
        for (int g = 0; g < 2; ++g)
            #pragma unroll
            for (int r = 0; r < 4; ++r) {
                int px = mt * 16 + quad * 4 + r;
                zbuf[((px * 32) + g * 16 + m) * 4 + w] = acc[mt][g][r];
            }
    __syncthreads();

    // read 4 gates per cell as float4; cell c = j*256 + tid (conflict-free:
    // consecutive lanes -> consecutive 16 B); fch = c&31, px = c>>5.
    {
        const int chbase = nh * 32;
        #pragma unroll
        for (int j = 0; j < 8; ++j) {
            int c = j * 256 + tid;
            int fch = c & 31, px = c >> 5;
            int py = px >> 3, pxx = px & 7;
            float4 z = *(const float4*)(zbuf + (size_t)c * 4);
            size_t gidx = (((size_t)b * 64 + (gy0 + py)) * 64 + (gx0 + pxx)) * 64 + chbase + fch;
            float c_prev = HP ? c_st[gidx] : 0.0f;
            float cn = hsig(z.y) * c_prev + hsig(z.x) * fmaxf(z.z, 0.0f);
            float hn = hsig(z.w) * fmaxf(cn, 0.0f);
            if (is_last) {
                c_st[gidx] = hn;            // d_out gets final h (fp32)
            } else {
                c_st[gidx] = cn;
                h_out[gidx] = f2bf(hn);
            }
        }
    }
}

extern "C" void kernel_launch(void* const* d_in, const int* in_sizes, int n_in,
                              void* d_out, int out_size, void* d_ws, size_t ws_size,
                              hipStream_t stream) {
    const float* x  = (const float*)d_in[0];
    const float* Wg = (const float*)d_in[1];
    const float* Ug = (const float*)d_in[2];
    const float* bs = (const float*)d_in[3];

    // ws layout: [packed weights 442368 B][h0 bf16 4 MB][h1 bf16 4 MB]
    unsigned short* wpk = (unsigned short*)d_ws;
    unsigned short* h0  = (unsigned short*)((char*)d_ws + 27 * 16 * 64 * 8 * 2);
    unsigned short* h1  = h0 + (size_t)8 * 64 * 64 * 64;
    float* cS = (float*)d_out;

    prepack_w<<<108, 256, 0, stream>>>(Wg, Ug, wpk);

    dim3 grid(8, 8, 16);   // 8x8 spatial tiles, z = b*2 + n-half
    dim3 block(256);
    for (int t = 0; t < TSTEPS; ++t) {
        const unsigned short* hin = (t == 0) ? h0 : ((t & 1) ? h0 : h1);
        unsigned short* hout = (t & 1) ? h1 : h0;
        if (t == 0) {
            convlstm_step<9><<<grid, block, 0, stream>>>(x, wpk, bs, hin, cS, hout, t, 0);
        } else {
            convlstm_step<27><<<grid, block, 0, stream>>>(x, wpk, bs, hin, cS, hout,
                                                          t, (t == TSTEPS - 1) ? 1 : 0);
        }
    }
}